// Round 2
// baseline (198.415 us; speedup 1.0000x reference)
//
#include <hip/hip_runtime.h>
#include <math.h>

#define B_ 16
#define F_ 256
#define T_ 2048
#define K_ 20
#define OUTK 21

// Transpose [F][Lsrc] (col offset co) -> [T][F] per batch, plus per-column sum of squares.
__global__ __launch_bounds__(256) void transpose_norm_kernel(
    const float* __restrict__ src, float* __restrict__ dst,
    float* __restrict__ nrm, int Lsrc, int co)
{
    __shared__ float tile[256][33];  // 256 f x 32 t, +1 pad
    int b  = blockIdx.y;
    int t0 = blockIdx.x * 32;
    const float* srcb = src + (size_t)b * F_ * Lsrc;
    int tl = threadIdx.x & 31;   // t within tile
    int fl = threadIdx.x >> 5;   // 0..7
#pragma unroll
    for (int i = 0; i < 32; ++i) {
        int f = i * 8 + fl;
        tile[f][tl] = srcb[(size_t)f * Lsrc + (t0 + tl + co)];
    }
    __syncthreads();
    float* dstb = dst + ((size_t)b * T_ + t0) * F_;
#pragma unroll
    for (int j = 0; j < 32; ++j) {
        dstb[(size_t)j * F_ + threadIdx.x] = tile[threadIdx.x][j];
    }
    if (threadIdx.x < 32) {
        float s = 0.f;
#pragma unroll 8
        for (int f = 0; f < 256; ++f) { float v = tile[f][threadIdx.x]; s += v * v; }
        nrm[b * T_ + t0 + threadIdx.x] = s;
    }
}

// Quad (4-lane) sum via DPP quad_perm — pure VALU, no DS ops.
__device__ __forceinline__ float quad_reduce_add(float d) {
    int y = __builtin_amdgcn_mov_dpp(__float_as_int(d), 0xB1, 0xF, 0xF, true); // xor 1
    d += __int_as_float(y);
    y = __builtin_amdgcn_mov_dpp(__float_as_int(d), 0x4E, 0xF, 0xF, true);     // xor 2
    d += __int_as_float(y);
    return d;
}

// One wave per (b,t); 16 quad-groups each own one target per round (2 rounds for 21).
__global__ __launch_bounds__(256) void sim_kernel(
    const float* __restrict__ zt, const float* __restrict__ ct,
    const float* __restrict__ nz, const float* __restrict__ nc,
    const int* __restrict__ inds, float* __restrict__ out)
{
    int i = blockIdx.x;                      // 8192 blocks, 4 waves each
    // XCD affinity: xcd = i % 8; batch b lives on XCD b % 8 (2 MB table -> L2-resident)
    int b  = (i & 7) + ((i >= 4096) ? 8 : 0);
    int t  = (((i >> 3) & 511) << 2) + (threadIdx.x >> 6);
    int bt = (b << 11) + t;
    int lane = threadIdx.x & 63;
    int g = lane >> 2;                       // group 0..15 (one target each)
    int q = lane & 3;                        // quarter 0..3 (64 floats each)

    const float4* zrow = (const float4*)(zt + (size_t)bt * F_);
    float4 zq[16];
#pragma unroll
    for (int j = 0; j < 16; ++j) zq[j] = zrow[q * 16 + j];

    float sqnz   = sqrtf(nz[bt]);
    float cfirst = ct[(size_t)bt * F_ + q * 64];   // for cheap equality check
    const int* myinds = inds + (size_t)bt * K_;
    float* orow = out + (size_t)bt * OUTK;

#pragma unroll
    for (int r = 0; r < 2; ++r) {
        int k = r * 16 + g;
        bool active = (k < OUTK);
        int row = bt;
        const float4* trow = (const float4*)(ct + (size_t)bt * F_);  // k==0: positive
        if (active && k > 0) {
            int idx = myinds[k - 1];                  // in [0, T-2]
            row  = (b << 11) + idx;
            trow = (const float4*)(zt + (size_t)row * F_);
        }

        float d = 0.f;
        float tfirst = 0.f;
        if (active) {
#pragma unroll
            for (int j = 0; j < 16; ++j) {
                float4 tv = trow[q * 16 + j];
                if (j == 0) tfirst = tv.x;
                d += zq[j].x * tv.x + zq[j].y * tv.y + zq[j].z * tv.z + zq[j].w * tv.w;
            }
        }
        d = quad_reduce_add(d);

        // exact neg_is_pos: cheap 1-element check, rare full fp32 recheck
        bool cheap = active && (k > 0) && (tfirst == cfirst);
        unsigned long long ball = __ballot(cheap);
        bool maskinf = false;
        if (((ball >> (g * 4)) & 0xFULL) == 0xFULL) {
            const float4* crow = (const float4*)(ct + (size_t)bt * F_);
            bool e = true;
#pragma unroll
            for (int j = 0; j < 16; ++j) {
                float4 cv = crow[q * 16 + j];
                float4 tv = trow[q * 16 + j];
                e = e && (cv.x == tv.x) && (cv.y == tv.y) && (cv.z == tv.z) && (cv.w == tv.w);
            }
            unsigned long long b2 = __ballot(e);
            maskinf = (((b2 >> (g * 4)) & 0xFULL) == 0xFULL);
        }

        if (active && q == 0) {
            float tn  = (k == 0) ? nc[bt] : nz[row];
            float den = fmaxf(sqnz * sqrtf(tn), 1e-8f);
            float v   = (d / den) * 2.0f;              // / TEMP, TEMP = 0.5
            orow[k] = maskinf ? -INFINITY : v;
        }
    }
}

extern "C" void kernel_launch(void* const* d_in, const int* in_sizes, int n_in,
                              void* d_out, int out_size, void* d_ws, size_t ws_size,
                              hipStream_t stream)
{
    const float* z    = (const float*)d_in[0];
    const float* c    = (const float*)d_in[1];
    const int*   inds = (const int*)d_in[2];
    float* out = (float*)d_out;

    char* ws = (char*)d_ws;
    size_t zt_bytes = (size_t)B_ * T_ * F_ * sizeof(float);  // 32 MB
    float* zt = (float*)ws;
    float* ct = (float*)(ws + zt_bytes);
    float* nz = (float*)(ws + 2 * zt_bytes);
    float* nc = nz + B_ * T_;

    dim3 tb(256), tg(T_ / 32, B_);
    transpose_norm_kernel<<<tg, tb, 0, stream>>>(z, zt, nz, T_, 0);
    transpose_norm_kernel<<<tg, tb, 0, stream>>>(c, ct, nc, T_ + 1, 1);
    sim_kernel<<<dim3(B_ * T_ / 4), dim3(256), 0, stream>>>(zt, ct, nz, nc, inds, out);
}

// Round 3
// 99.548 us; speedup vs baseline: 1.9932x; 1.9932x over previous
//
#include <hip/hip_runtime.h>
#include <math.h>

#define B_ 16
#define F_ 256
#define T_ 2048
#define K_ 20
#define OUTK 21

// Fused transpose of z [F][T] and c [F][T+1] (drop col 0) -> [T][F] per batch,
// plus per-column sum of squares. blockIdx.z selects z (0) or c (1).
__global__ __launch_bounds__(256) void transpose_norm2_kernel(
    const float* __restrict__ z, const float* __restrict__ c,
    float* __restrict__ zt, float* __restrict__ ct,
    float* __restrict__ nz, float* __restrict__ nc)
{
    __shared__ float tile[256][33];  // 256 f x 32 t, +1 pad
    int which = blockIdx.z;
    const float* src = which ? c : z;
    float* dst = which ? ct : zt;
    float* nrm = which ? nc : nz;
    int Lsrc = which ? (T_ + 1) : T_;
    int co   = which;                 // c drops the start token

    int b  = blockIdx.y;
    int t0 = blockIdx.x * 32;
    const float* srcb = src + (size_t)b * F_ * Lsrc;
    int tl = threadIdx.x & 31;   // t within tile
    int fl = threadIdx.x >> 5;   // 0..7
#pragma unroll
    for (int i = 0; i < 32; ++i) {
        int f = i * 8 + fl;
        tile[f][tl] = srcb[(size_t)f * Lsrc + (t0 + tl + co)];
    }
    __syncthreads();
    float* dstb = dst + ((size_t)b * T_ + t0) * F_;
#pragma unroll
    for (int j = 0; j < 32; ++j) {
        dstb[(size_t)j * F_ + threadIdx.x] = tile[threadIdx.x][j];
    }
    if (threadIdx.x < 32) {
        float s = 0.f;
#pragma unroll 8
        for (int f = 0; f < 256; ++f) { float v = tile[f][threadIdx.x]; s += v * v; }
        nrm[b * T_ + t0 + threadIdx.x] = s;
    }
}

// Pure-VALU wave sum via DPP (no LDS-pipe ops). Result valid in lane 63.
__device__ __forceinline__ float dpp_wave_sum63(float x) {
    x += __int_as_float(__builtin_amdgcn_mov_dpp(__float_as_int(x), 0x111, 0xF, 0xF, true)); // row_shr:1
    x += __int_as_float(__builtin_amdgcn_mov_dpp(__float_as_int(x), 0x112, 0xF, 0xF, true)); // row_shr:2
    x += __int_as_float(__builtin_amdgcn_mov_dpp(__float_as_int(x), 0x114, 0xF, 0xF, true)); // row_shr:4
    x += __int_as_float(__builtin_amdgcn_mov_dpp(__float_as_int(x), 0x118, 0xF, 0xF, true)); // row_shr:8
    x += __int_as_float(__builtin_amdgcn_mov_dpp(__float_as_int(x), 0x142, 0xF, 0xF, true)); // row_bcast:15
    x += __int_as_float(__builtin_amdgcn_mov_dpp(__float_as_int(x), 0x143, 0xF, 0xF, true)); // row_bcast:31
    return x;
}

// One 64-lane wave per (b,t): 21 cosine sims. Coalesced full-row loads,
// batch->XCD affinity so each XCD's L2 holds its 2 batches of zt (4 MB).
__global__ __launch_bounds__(256) void sim_kernel(
    const float* __restrict__ zt, const float* __restrict__ ct,
    const float* __restrict__ nz, const float* __restrict__ nc,
    const int* __restrict__ inds, float* __restrict__ out)
{
    int i = blockIdx.x;                               // 8192 blocks, 4 waves each
    int b = (i & 7) | ((i >= 4096) ? 8 : 0);          // batch b on XCD b&7
    int t = (((i >> 3) & 511) << 2) + (threadIdx.x >> 6);
    int lane = threadIdx.x & 63;
    int bt = __builtin_amdgcn_readfirstlane((b << 11) + t);

    const float4* zrow = (const float4*)(zt + (size_t)bt * F_);
    const float4* crow = (const float4*)(ct + (size_t)bt * F_);
    float4 zv = zrow[lane];
    float4 cv = crow[lane];

    const int* myinds = inds + bt * K_;
    int rows[OUTK];
    rows[0] = bt;
#pragma unroll
    for (int k = 0; k < K_; ++k)
        rows[k + 1] = __builtin_amdgcn_readfirstlane((b << 11) + myinds[k]);

    float d[OUTK];
    bool  m[OUTK];
#pragma unroll
    for (int k = 0; k < OUTK; ++k) {
        const float4* trow = (k == 0) ? crow : (const float4*)(zt + (size_t)rows[k] * F_);
        float4 tv = trow[lane];
        float dd = fmaf(zv.x, tv.x, fmaf(zv.y, tv.y, fmaf(zv.z, tv.z, zv.w * tv.w)));
        if (k > 0) {
            bool eq = (tv.x == cv.x) & (tv.y == cv.y) & (tv.z == cv.z) & (tv.w == cv.w);
            m[k] = (bool)__all(eq);                   // exact fp32 neg_is_pos
        } else {
            m[k] = false;
        }
        d[k] = dpp_wave_sum63(dd);
    }

    if (lane == 63) {
        float sqnz = sqrtf(nz[bt]);
        float* orow = out + (size_t)bt * OUTK;
#pragma unroll
        for (int k = 0; k < OUTK; ++k) {
            float tn  = (k == 0) ? nc[bt] : nz[rows[k]];
            float den = fmaxf(sqnz * sqrtf(tn), 1e-8f);
            float v   = (d[k] / den) * 2.0f;          // / TEMP, TEMP = 0.5
            orow[k] = m[k] ? -INFINITY : v;
        }
    }
}

extern "C" void kernel_launch(void* const* d_in, const int* in_sizes, int n_in,
                              void* d_out, int out_size, void* d_ws, size_t ws_size,
                              hipStream_t stream)
{
    const float* z    = (const float*)d_in[0];
    const float* c    = (const float*)d_in[1];
    const int*   inds = (const int*)d_in[2];
    float* out = (float*)d_out;

    char* ws = (char*)d_ws;
    size_t zt_bytes = (size_t)B_ * T_ * F_ * sizeof(float);  // 32 MB
    float* zt = (float*)ws;
    float* ct = (float*)(ws + zt_bytes);
    float* nz = (float*)(ws + 2 * zt_bytes);
    float* nc = nz + B_ * T_;

    dim3 tb(256), tg(T_ / 32, B_, 2);
    transpose_norm2_kernel<<<tg, tb, 0, stream>>>(z, c, zt, ct, nz, nc);
    sim_kernel<<<dim3(B_ * T_ / 4), dim3(256), 0, stream>>>(zt, ct, nz, nc, inds, out);
}

// Round 4
// 69.027 us; speedup vs baseline: 2.8745x; 1.4422x over previous
//
#include <hip/hip_runtime.h>
#include <hip/hip_fp16.h>
#include <math.h>

#define B_ 16
#define F_ 256
#define T_ 2048
#define K_ 20
#define OUTK 21

typedef _Float16 half2v __attribute__((ext_vector_type(2)));

__device__ __forceinline__ half2v h2(unsigned u) {
    return __builtin_bit_cast(half2v, u);
}
__device__ __forceinline__ float fdot2f(unsigned a, unsigned b, float c) {
#if __has_builtin(__builtin_amdgcn_fdot2)
    return __builtin_amdgcn_fdot2(h2(a), h2(b), c, false);
#else
    half2v x = h2(a), y = h2(b);
    return fmaf((float)x[1], (float)y[1], fmaf((float)x[0], (float)y[0], c));
#endif
}

// Transpose z [F][T] / c [F][T+1] (drop col 0) -> f16 [T][F] per batch,
// plus per-column sqrt(sum of squares) in fp32 (exact, from fp32 source).
__global__ __launch_bounds__(256) void transpose_norm2_kernel(
    const float* __restrict__ z, const float* __restrict__ c,
    ushort* __restrict__ zth, ushort* __restrict__ cth,
    float* __restrict__ snz, float* __restrict__ snc)
{
    __shared__ float tile[256][33];  // 256 f x 32 t, +1 pad
    int which = blockIdx.z;
    const float* src = which ? c : z;
    ushort* dst = which ? cth : zth;
    float* nrm = which ? snc : snz;
    int Lsrc = which ? (T_ + 1) : T_;
    int co   = which;                 // c drops the start token

    int b  = blockIdx.y;
    int t0 = blockIdx.x * 32;
    const float* srcb = src + (size_t)b * F_ * Lsrc;
    int tl = threadIdx.x & 31;   // t within tile
    int fl = threadIdx.x >> 5;   // 0..7
#pragma unroll
    for (int i = 0; i < 32; ++i) {
        int f = i * 8 + fl;
        tile[f][tl] = srcb[(size_t)f * Lsrc + (t0 + tl + co)];
    }
    __syncthreads();
    // write phase: pack 2 adjacent f into one uint; 128 lanes cover a row, 2 rows/iter
    int l   = threadIdx.x & 127;
    int rhi = threadIdx.x >> 7;
#pragma unroll
    for (int j2 = 0; j2 < 16; ++j2) {
        int row = j2 * 2 + rhi;
        float a  = tile[2 * l][row];
        float bb = tile[2 * l + 1][row];
        unsigned u = ((unsigned)__half_as_ushort(__float2half(bb)) << 16)
                   |  (unsigned)__half_as_ushort(__float2half(a));
        unsigned* drow = (unsigned*)(dst + ((size_t)b * T_ + t0 + row) * F_);
        drow[l] = u;
    }
    if (threadIdx.x < 32) {
        float s = 0.f;
#pragma unroll 8
        for (int f = 0; f < 256; ++f) { float v = tile[f][threadIdx.x]; s += v * v; }
        nrm[b * T_ + t0 + threadIdx.x] = sqrtf(s);
    }
}

// Pure-VALU wave sum via DPP. Result valid in lane 63.
__device__ __forceinline__ float dpp_wave_sum63(float x) {
    x += __int_as_float(__builtin_amdgcn_mov_dpp(__float_as_int(x), 0x111, 0xF, 0xF, true)); // row_shr:1
    x += __int_as_float(__builtin_amdgcn_mov_dpp(__float_as_int(x), 0x112, 0xF, 0xF, true)); // row_shr:2
    x += __int_as_float(__builtin_amdgcn_mov_dpp(__float_as_int(x), 0x114, 0xF, 0xF, true)); // row_shr:4
    x += __int_as_float(__builtin_amdgcn_mov_dpp(__float_as_int(x), 0x118, 0xF, 0xF, true)); // row_shr:8
    x += __int_as_float(__builtin_amdgcn_mov_dpp(__float_as_int(x), 0x142, 0xF, 0xF, true)); // row_bcast:15
    x += __int_as_float(__builtin_amdgcn_mov_dpp(__float_as_int(x), 0x143, 0xF, 0xF, true)); // row_bcast:31
    return x;
}

// One 64-lane wave per (b,t): 21 cosine sims, f16 rows (512B), all targets
// prefetched into registers (21 loads in flight), then interleaved DPP reduces.
__global__ __launch_bounds__(256) void sim_kernel(
    const ushort* __restrict__ zth, const ushort* __restrict__ cth,
    const float* __restrict__ snz, const float* __restrict__ snc,
    const int* __restrict__ inds, float* __restrict__ out)
{
    int i = blockIdx.x;                               // 8192 blocks, 4 waves each
    int b = (i & 7) | ((i >= 4096) ? 8 : 0);          // batch b on XCD b&7 (L2-resident table)
    int t = (((i >> 3) & 511) << 2) + (threadIdx.x >> 6);
    int lane = threadIdx.x & 63;
    int bt = __builtin_amdgcn_readfirstlane((b << 11) + t);

    const uint2* zrow = (const uint2*)(zth + (size_t)bt * F_);
    const uint2* crow = (const uint2*)(cth + (size_t)bt * F_);
    uint2 zv = zrow[lane];
    uint2 cv = crow[lane];

    const int* myinds = inds + bt * K_;
    int rows[OUTK];
    rows[0] = bt;
#pragma unroll
    for (int k = 0; k < K_; ++k)
        rows[k + 1] = __builtin_amdgcn_readfirstlane((b << 11) + myinds[k]);

    // prefetch ALL target rows -> 21 loads in flight
    uint2 tv[OUTK];
    tv[0] = cv;
#pragma unroll
    for (int k = 1; k < OUTK; ++k)
        tv[k] = ((const uint2*)(zth + (size_t)rows[k] * F_))[lane];

    unsigned maskbits = 0;
    float d[OUTK];
#pragma unroll
    for (int k = 0; k < OUTK; ++k) {
        d[k] = fdot2f(tv[k].x, zv.x, fdot2f(tv[k].y, zv.y, 0.f));
        if (k > 0) {
            bool eq = (tv[k].x == cv.x) && (tv[k].y == cv.y);
            maskbits |= (unsigned)(__all(eq) ? 1 : 0) << k;   // uniform
        }
    }
#pragma unroll
    for (int k = 0; k < OUTK; ++k) d[k] = dpp_wave_sum63(d[k]);

    if (lane == 63) {
        float sz = snz[bt];
        float* orow = out + (size_t)bt * OUTK;
#pragma unroll
        for (int k = 0; k < OUTK; ++k) {
            float st  = (k == 0) ? snc[bt] : snz[rows[k]];
            float den = fmaxf(sz * st, 1e-8f);
            float v   = (d[k] / den) * 2.0f;          // / TEMP, TEMP = 0.5
            orow[k] = ((maskbits >> k) & 1u) ? -INFINITY : v;
        }
    }
}

extern "C" void kernel_launch(void* const* d_in, const int* in_sizes, int n_in,
                              void* d_out, int out_size, void* d_ws, size_t ws_size,
                              hipStream_t stream)
{
    const float* z    = (const float*)d_in[0];
    const float* c    = (const float*)d_in[1];
    const int*   inds = (const int*)d_in[2];
    float* out = (float*)d_out;

    char* ws = (char*)d_ws;
    size_t th_bytes = (size_t)B_ * T_ * F_ * sizeof(ushort);  // 16 MB
    ushort* zth = (ushort*)ws;
    ushort* cth = (ushort*)(ws + th_bytes);
    float*  snz = (float*)(ws + 2 * th_bytes);
    float*  snc = snz + B_ * T_;

    dim3 tb(256), tg(T_ / 32, B_, 2);
    transpose_norm2_kernel<<<tg, tb, 0, stream>>>(z, c, zth, cth, snz, snc);
    sim_kernel<<<dim3(B_ * T_ / 4), dim3(256), 0, stream>>>(zth, cth, snz, snc, inds, out);
}

// Round 5
// 68.463 us; speedup vs baseline: 2.8981x; 1.0082x over previous
//
#include <hip/hip_runtime.h>
#include <hip/hip_fp16.h>
#include <math.h>

#define B_ 16
#define F_ 256
#define T_ 2048
#define K_ 20
#define OUTK 21

typedef _Float16 half2v __attribute__((ext_vector_type(2)));

__device__ __forceinline__ half2v h2(unsigned u) {
    return __builtin_bit_cast(half2v, u);
}
__device__ __forceinline__ float fdot2f(unsigned a, unsigned b, float c) {
#if __has_builtin(__builtin_amdgcn_fdot2)
    return __builtin_amdgcn_fdot2(h2(a), h2(b), c, false);
#else
    half2v x = h2(a), y = h2(b);
    return fmaf((float)x[1], (float)y[1], fmaf((float)x[0], (float)y[0], c));
#endif
}

// Transpose z [F][T] / c [F][T+1] (drop col 0) -> f16 [T][F] per batch,
// plus per-column sqrt(sum of squares) in fp32 (exact, from fp32 source).
__global__ __launch_bounds__(256) void transpose_norm2_kernel(
    const float* __restrict__ z, const float* __restrict__ c,
    ushort* __restrict__ zth, ushort* __restrict__ cth,
    float* __restrict__ snz, float* __restrict__ snc)
{
    __shared__ float tile[256][33];  // 256 f x 32 t, +1 pad
    int which = blockIdx.z;
    const float* src = which ? c : z;
    ushort* dst = which ? cth : zth;
    float* nrm = which ? snc : snz;
    int Lsrc = which ? (T_ + 1) : T_;
    int co   = which;                 // c drops the start token

    int b  = blockIdx.y;
    int t0 = blockIdx.x * 32;
    const float* srcb = src + (size_t)b * F_ * Lsrc;
    int tl = threadIdx.x & 31;   // t within tile
    int fl = threadIdx.x >> 5;   // 0..7
#pragma unroll
    for (int i = 0; i < 32; ++i) {
        int f = i * 8 + fl;
        tile[f][tl] = srcb[(size_t)f * Lsrc + (t0 + tl + co)];
    }
    __syncthreads();
    // write phase: pack 2 adjacent f into one uint; 128 lanes cover a row, 2 rows/iter
    int l   = threadIdx.x & 127;
    int rhi = threadIdx.x >> 7;
#pragma unroll
    for (int j2 = 0; j2 < 16; ++j2) {
        int row = j2 * 2 + rhi;
        float a  = tile[2 * l][row];
        float bb = tile[2 * l + 1][row];
        unsigned u = ((unsigned)__half_as_ushort(__float2half(bb)) << 16)
                   |  (unsigned)__half_as_ushort(__float2half(a));
        unsigned* drow = (unsigned*)(dst + ((size_t)b * T_ + t0 + row) * F_);
        drow[l] = u;
    }
    if (threadIdx.x < 32) {
        float s = 0.f;
#pragma unroll 8
        for (int f = 0; f < 256; ++f) { float v = tile[f][threadIdx.x]; s += v * v; }
        nrm[b * T_ + t0 + threadIdx.x] = sqrtf(s);
    }
}

// Pure-VALU wave sum via DPP. Result valid in lane 63.
__device__ __forceinline__ float dpp_wave_sum63(float x) {
    x += __int_as_float(__builtin_amdgcn_mov_dpp(__float_as_int(x), 0x111, 0xF, 0xF, true)); // row_shr:1
    x += __int_as_float(__builtin_amdgcn_mov_dpp(__float_as_int(x), 0x112, 0xF, 0xF, true)); // row_shr:2
    x += __int_as_float(__builtin_amdgcn_mov_dpp(__float_as_int(x), 0x114, 0xF, 0xF, true)); // row_shr:4
    x += __int_as_float(__builtin_amdgcn_mov_dpp(__float_as_int(x), 0x118, 0xF, 0xF, true)); // row_shr:8
    x += __int_as_float(__builtin_amdgcn_mov_dpp(__float_as_int(x), 0x142, 0xF, 0xF, true)); // row_bcast:15
    x += __int_as_float(__builtin_amdgcn_mov_dpp(__float_as_int(x), 0x143, 0xF, 0xF, true)); // row_bcast:31
    return x;
}

// One 64-lane wave per (b,t): 21 cosine sims, f16 rows (512B), all targets
// HELD in registers via asm pins so the compiler cannot sink the loads.
__global__ __launch_bounds__(256) void sim_kernel(
    const ushort* __restrict__ zth, const ushort* __restrict__ cth,
    const float* __restrict__ snz, const float* __restrict__ snc,
    const int* __restrict__ inds, float* __restrict__ out)
{
    int i = blockIdx.x;                               // 8192 blocks, 4 waves each
    int b = (i & 7) | ((i >= 4096) ? 8 : 0);          // batch b on XCD b&7 (L2-resident table)
    int t = (((i >> 3) & 511) << 2) + (threadIdx.x >> 6);
    int lane = threadIdx.x & 63;
    int bt = __builtin_amdgcn_readfirstlane((b << 11) + t);

    const uint2* zrow = (const uint2*)(zth + (size_t)bt * F_);
    const uint2* crow = (const uint2*)(cth + (size_t)bt * F_);
    uint2 zv = zrow[lane];
    uint2 cv = crow[lane];

    const int* myinds = inds + bt * K_;
    int rows[OUTK];
    rows[0] = bt;
#pragma unroll
    for (int k = 0; k < K_; ++k)
        rows[k + 1] = __builtin_amdgcn_readfirstlane((b << 11) + myinds[k]);

    // prefetch ALL target rows -> 21 loads in flight
    uint2 tv[OUTK];
    tv[0] = cv;
#pragma unroll
    for (int k = 1; k < OUTK; ++k)
        tv[k] = ((const uint2*)(zth + (size_t)rows[k] * F_))[lane];

    // pin: forbid the compiler from sinking the loads to their use sites
#pragma unroll
    for (int k = 1; k < OUTK; ++k)
        asm volatile("" : "+v"(tv[k].x), "+v"(tv[k].y));

    unsigned maskbits = 0;
    float d[OUTK];
#pragma unroll
    for (int k = 0; k < OUTK; ++k) {
        d[k] = fdot2f(tv[k].x, zv.x, fdot2f(tv[k].y, zv.y, 0.f));
        if (k > 0) {
            bool eq = (tv[k].x == cv.x) && (tv[k].y == cv.y);
            maskbits |= (unsigned)(__all(eq) ? 1 : 0) << k;   // uniform
        }
    }
#pragma unroll
    for (int k = 0; k < OUTK; ++k) d[k] = dpp_wave_sum63(d[k]);

    if (lane == 63) {
        float sz = snz[bt];
        float* orow = out + (size_t)bt * OUTK;
#pragma unroll
        for (int k = 0; k < OUTK; ++k) {
            float st  = (k == 0) ? snc[bt] : snz[rows[k]];
            float den = fmaxf(sz * st, 1e-8f);
            float v   = (d[k] / den) * 2.0f;          // / TEMP, TEMP = 0.5
            orow[k] = ((maskbits >> k) & 1u) ? -INFINITY : v;
        }
    }
}

extern "C" void kernel_launch(void* const* d_in, const int* in_sizes, int n_in,
                              void* d_out, int out_size, void* d_ws, size_t ws_size,
                              hipStream_t stream)
{
    const float* z    = (const float*)d_in[0];
    const float* c    = (const float*)d_in[1];
    const int*   inds = (const int*)d_in[2];
    float* out = (float*)d_out;

    char* ws = (char*)d_ws;
    size_t th_bytes = (size_t)B_ * T_ * F_ * sizeof(ushort);  // 16 MB
    ushort* zth = (ushort*)ws;
    ushort* cth = (ushort*)(ws + th_bytes);
    float*  snz = (float*)(ws + 2 * th_bytes);
    float*  snc = snz + B_ * T_;

    dim3 tb(256), tg(T_ / 32, B_, 2);
    transpose_norm2_kernel<<<tg, tb, 0, stream>>>(z, c, zth, cth, snz, snc);
    sim_kernel<<<dim3(B_ * T_ / 4), dim3(256), 0, stream>>>(zth, cth, snz, snc, inds, out);
}

// Round 6
// 67.964 us; speedup vs baseline: 2.9194x; 1.0073x over previous
//
#include <hip/hip_runtime.h>
#include <hip/hip_fp16.h>
#include <math.h>

#define B_ 16
#define F_ 256
#define T_ 2048
#define K_ 20
#define OUTK 21

typedef _Float16 half2v __attribute__((ext_vector_type(2)));

__device__ __forceinline__ half2v h2(unsigned u) {
    return __builtin_bit_cast(half2v, u);
}
__device__ __forceinline__ float fdot2f(unsigned a, unsigned b, float c) {
#if __has_builtin(__builtin_amdgcn_fdot2)
    return __builtin_amdgcn_fdot2(h2(a), h2(b), c, false);
#else
    half2v x = h2(a), y = h2(b);
    return fmaf((float)x[1], (float)y[1], fmaf((float)x[0], (float)y[0], c));
#endif
}

// Transpose z [F][T] / c [F][T+1] (drop col 0) -> f16 [T][F] per batch,
// plus per-column sqrt(sum of squares) in fp32 (exact, from fp32 source).
__global__ __launch_bounds__(256) void transpose_norm2_kernel(
    const float* __restrict__ z, const float* __restrict__ c,
    ushort* __restrict__ zth, ushort* __restrict__ cth,
    float* __restrict__ snz, float* __restrict__ snc)
{
    __shared__ float tile[256][33];  // 256 f x 32 t, +1 pad
    int which = blockIdx.z;
    const float* src = which ? c : z;
    ushort* dst = which ? cth : zth;
    float* nrm = which ? snc : snz;
    int Lsrc = which ? (T_ + 1) : T_;
    int co   = which;                 // c drops the start token

    int b  = blockIdx.y;
    int t0 = blockIdx.x * 32;
    const float* srcb = src + (size_t)b * F_ * Lsrc;
    int tl = threadIdx.x & 31;   // t within tile
    int fl = threadIdx.x >> 5;   // 0..7
#pragma unroll
    for (int i = 0; i < 32; ++i) {
        int f = i * 8 + fl;
        tile[f][tl] = srcb[(size_t)f * Lsrc + (t0 + tl + co)];
    }
    __syncthreads();
    // write phase: pack 2 adjacent f into one uint; 128 lanes cover a row, 2 rows/iter
    int l   = threadIdx.x & 127;
    int rhi = threadIdx.x >> 7;
#pragma unroll
    for (int j2 = 0; j2 < 16; ++j2) {
        int row = j2 * 2 + rhi;
        float a  = tile[2 * l][row];
        float bb = tile[2 * l + 1][row];
        unsigned u = ((unsigned)__half_as_ushort(__float2half(bb)) << 16)
                   |  (unsigned)__half_as_ushort(__float2half(a));
        unsigned* drow = (unsigned*)(dst + ((size_t)b * T_ + t0 + row) * F_);
        drow[l] = u;
    }
    if (threadIdx.x < 32) {
        float s = 0.f;
#pragma unroll 8
        for (int f = 0; f < 256; ++f) { float v = tile[f][threadIdx.x]; s += v * v; }
        nrm[b * T_ + t0 + threadIdx.x] = sqrtf(s);
    }
}

// Pure-VALU wave sum via DPP. Result valid in lane 63.
__device__ __forceinline__ float dpp_wave_sum63(float x) {
    x += __int_as_float(__builtin_amdgcn_mov_dpp(__float_as_int(x), 0x111, 0xF, 0xF, true)); // row_shr:1
    x += __int_as_float(__builtin_amdgcn_mov_dpp(__float_as_int(x), 0x112, 0xF, 0xF, true)); // row_shr:2
    x += __int_as_float(__builtin_amdgcn_mov_dpp(__float_as_int(x), 0x114, 0xF, 0xF, true)); // row_shr:4
    x += __int_as_float(__builtin_amdgcn_mov_dpp(__float_as_int(x), 0x118, 0xF, 0xF, true)); // row_shr:8
    x += __int_as_float(__builtin_amdgcn_mov_dpp(__float_as_int(x), 0x142, 0xF, 0xF, true)); // row_bcast:15
    x += __int_as_float(__builtin_amdgcn_mov_dpp(__float_as_int(x), 0x143, 0xF, 0xF, true)); // row_bcast:31
    return x;
}

// One 64-lane wave per (b,t): 21 cosine sims, f16 rows (512B). All 21 target
// loads are issued before a memory-clobber asm barrier -> loads cannot sink
// to their use sites -> 21 loads in flight per wave (true prefetch).
__global__ __launch_bounds__(256) void sim_kernel(
    const ushort* __restrict__ zth, const ushort* __restrict__ cth,
    const float* __restrict__ snz, const float* __restrict__ snc,
    const int* __restrict__ inds, float* __restrict__ out)
{
    int i = blockIdx.x;                               // 8192 blocks, 4 waves each
    int b = (i & 7) | ((i >= 4096) ? 8 : 0);          // batch b on XCD b&7 (L2-resident table)
    int t = (((i >> 3) & 511) << 2) + (threadIdx.x >> 6);
    int lane = threadIdx.x & 63;
    int bt = __builtin_amdgcn_readfirstlane((b << 11) + t);

    const uint2* zrow = (const uint2*)(zth + (size_t)bt * F_);
    const uint2* crow = (const uint2*)(cth + (size_t)bt * F_);
    uint2 zv = zrow[lane];
    uint2 cv = crow[lane];

    const int* myinds = inds + bt * K_;
    int rows[OUTK];
    rows[0] = bt;
#pragma unroll
    for (int k = 0; k < K_; ++k)
        rows[k + 1] = __builtin_amdgcn_readfirstlane((b << 11) + myinds[k]);

    // prefetch ALL target rows -> 21 loads in flight
    uint2 tv[OUTK];
    tv[0] = cv;
#pragma unroll
    for (int k = 1; k < OUTK; ++k)
        tv[k] = ((const uint2*)(zth + (size_t)rows[k] * F_))[lane];

    // scheduling fence: loads (memory reads) cannot sink past a memory-clobber
    // asm, so all 21 are issued before any consumer below.
    asm volatile("" ::: "memory");

    unsigned maskbits = 0;
    float d[OUTK];
#pragma unroll
    for (int k = 0; k < OUTK; ++k) {
        d[k] = fdot2f(tv[k].x, zv.x, fdot2f(tv[k].y, zv.y, 0.f));
        if (k > 0) {
            bool eq = (tv[k].x == cv.x) && (tv[k].y == cv.y);
            maskbits |= (unsigned)(__all(eq) ? 1 : 0) << k;   // uniform
        }
    }
#pragma unroll
    for (int k = 0; k < OUTK; ++k) d[k] = dpp_wave_sum63(d[k]);

    if (lane == 63) {
        float sz = snz[bt];
        float* orow = out + (size_t)bt * OUTK;
#pragma unroll
        for (int k = 0; k < OUTK; ++k) {
            float st  = (k == 0) ? snc[bt] : snz[rows[k]];
            float den = fmaxf(sz * st, 1e-8f);
            float v   = (d[k] / den) * 2.0f;          // / TEMP, TEMP = 0.5
            orow[k] = ((maskbits >> k) & 1u) ? -INFINITY : v;
        }
    }
}

extern "C" void kernel_launch(void* const* d_in, const int* in_sizes, int n_in,
                              void* d_out, int out_size, void* d_ws, size_t ws_size,
                              hipStream_t stream)
{
    const float* z    = (const float*)d_in[0];
    const float* c    = (const float*)d_in[1];
    const int*   inds = (const int*)d_in[2];
    float* out = (float*)d_out;

    char* ws = (char*)d_ws;
    size_t th_bytes = (size_t)B_ * T_ * F_ * sizeof(ushort);  // 16 MB
    ushort* zth = (ushort*)ws;
    ushort* cth = (ushort*)(ws + th_bytes);
    float*  snz = (float*)(ws + 2 * th_bytes);
    float*  snc = snz + B_ * T_;

    dim3 tb(256), tg(T_ / 32, B_, 2);
    transpose_norm2_kernel<<<tg, tb, 0, stream>>>(z, c, zth, cth, snz, snc);
    sim_kernel<<<dim3(B_ * T_ / 4), dim3(256), 0, stream>>>(zth, cth, snz, snc, inds, out);
}